// Round 3
// baseline (500.681 us; speedup 1.0000x reference)
//
#include <hip/hip_runtime.h>
#include <hip/hip_bf16.h>
#include <cstdint>

#define NN   8192
#define HID  128

typedef __attribute__((ext_vector_type(8)))  __bf16          bf16x8;
typedef __attribute__((ext_vector_type(16))) float           f32x16;
typedef __attribute__((ext_vector_type(8)))  unsigned short  u16x8;
typedef __attribute__((ext_vector_type(4)))  unsigned short  u16x4;
typedef __attribute__((ext_vector_type(4)))  float           f32x4;

__device__ __forceinline__ float b2f(unsigned short u){
  union { unsigned int i; float f; } v; v.i = ((unsigned int)u) << 16; return v.f;
}
__device__ __forceinline__ unsigned short f2b(float f){
  unsigned int i = __float_as_uint(f);
  unsigned int r = (i + 0x7FFFu + ((i >> 16) & 1u)) >> 16;   // RNE
  return (unsigned short)r;
}
__device__ __forceinline__ void gld_lds16(const void* g, void* l){
  __builtin_amdgcn_global_load_lds((const __attribute__((address_space(1))) unsigned int*)g,
                                   (__attribute__((address_space(3))) unsigned int*)l, 16, 0, 0);
}

// ---------------- dtype detect: bf16 buffers -> flag=1, f32 -> flag=0 ----------------
__global__ __launch_bounds__(256) void k_detect(const unsigned int* __restrict__ a,
                                                int* __restrict__ flag){
  __shared__ int cnt;
  if(threadIdx.x == 0) cnt = 0;
  __syncthreads();
  int c = 0;
  #pragma unroll
  for(int i = 0; i < 16; ++i){
    unsigned int w = a[i * 256 + threadIdx.x];
    c += (((w >> 8) & 0xC0u) == 0u) ? 1 : 0;
  }
  atomicAdd(&cnt, c);
  __syncthreads();
  if(threadIdx.x == 0) *flag = (cnt > 3000) ? 1 : 0;
}

// -------- deg + inv_sqrt_deg, fused f32->bf16 adj convert (one wave per row) --------
__global__ __launch_bounds__(256) void k_degcvt(const void* __restrict__ adjv,
                                                const int* __restrict__ flagp,
                                                float* __restrict__ isd,
                                                unsigned short* __restrict__ adjb){
  const int wid = threadIdx.x >> 6, l = threadIdx.x & 63;
  const int row = blockIdx.x * 4 + wid;
  float s = 0.f;
  if(*flagp){
    const u16x8* rp = (const u16x8*)((const unsigned short*)adjv + (size_t)row * NN);
    #pragma unroll
    for(int it = 0; it < 16; ++it){
      u16x8 v = rp[it * 64 + l];
      #pragma unroll
      for(int j = 0; j < 8; ++j) s += b2f(v[j]);
    }
  } else {
    const f32x4* rp = (const f32x4*)((const float*)adjv + (size_t)row * NN);
    u16x4* wp = (u16x4*)(adjb + (size_t)row * NN);
    #pragma unroll
    for(int it = 0; it < 32; ++it){
      f32x4 v = rp[it * 64 + l];
      s += v[0] + v[1] + v[2] + v[3];
      u16x4 w;
      w[0] = f2b(v[0]); w[1] = f2b(v[1]); w[2] = f2b(v[2]); w[3] = f2b(v[3]);
      wp[it * 64 + l] = w;
    }
  }
  #pragma unroll
  for(int m = 32; m > 0; m >>= 1) s += __shfl_xor(s, m, 64);
  if(l == 0) isd[row] = (s > 0.f) ? rsqrtf(fmaxf(s, 1e-12f)) : 0.f;
}

// ---------------- feat0 = concat(pos, emb) as f32 ----------------
__global__ __launch_bounds__(256) void k_feat0(const void* __restrict__ pos,
                                               const void* __restrict__ emb,
                                               const int* __restrict__ flagp,
                                               float* __restrict__ feat){
  const int x = blockIdx.x * 256 + threadIdx.x;
  const int r = x >> 7, c = x & 127;
  float v;
  if(*flagp){
    v = b2f(c < 3 ? ((const unsigned short*)pos)[r * 3 + c]
                  : ((const unsigned short*)emb)[r * 125 + (c - 3)]);
  } else {
    v = (c < 3) ? ((const float*)pos)[r * 3 + c]
                : ((const float*)emb)[r * 125 + (c - 3)];
  }
  feat[x] = v;
}

// ---------------- W transpose to bf16: Wt[l][c][i] = bf16(Ws[l][i][c]) ----------------
__global__ __launch_bounds__(256) void k_wt(const void* __restrict__ Ws,
                                            const int* __restrict__ flagp,
                                            unsigned short* __restrict__ Wt){
  const int x = blockIdx.x * 256 + threadIdx.x;
  const int lyr = x >> 14, rem = x & 16383, i = rem >> 7, c = rem & 127;
  unsigned short u;
  if(*flagp) u = ((const unsigned short*)Ws)[x];
  else       u = f2b(((const float*)Ws)[x]);
  Wt[lyr * 16384 + c * 128 + i] = u;
}

// ---- shared core: A-tile (bf16, swizzled) already in lds[0,32K); do @W, write Bt ----
__device__ __forceinline__ void bcore(char* lds, const unsigned short* __restrict__ Wt,
                                      unsigned short* __restrict__ Bt, int r0, int t){
  const int wid = t >> 6, l = t & 63;
  // stage Wt (bf16, 256B rows) into [32K,64K), pre-swizzled source
  #pragma unroll
  for(int q = 0; q < 8; ++q){
    int ob = q * 4096 + wid * 1024;
    int o  = ob + l * 16;
    int c  = o >> 8, x = o & 255;
    gld_lds16((const char*)Wt + c * 256 + (x ^ ((c & 7) << 4)), lds + 32768 + ob);
  }
  __syncthreads();

  const int wm = wid >> 1, wn = wid & 1;
  f32x16 acc[2][2];
  #pragma unroll
  for(int a = 0; a < 2; ++a)
    #pragma unroll
    for(int b = 0; b < 2; ++b)
      #pragma unroll
      for(int r2 = 0; r2 < 16; ++r2) acc[a][b][r2] = 0.f;

  const int swz = (l & 7) << 4;
  #pragma unroll
  for(int st = 0; st < 8; ++st){
    int ko = (st * 32 + ((l >> 5) << 4)) ^ swz;
    bf16x8 a0 = *(const bf16x8*)(lds + (wm * 64 +      (l & 31)) * 256 + ko);
    bf16x8 a1 = *(const bf16x8*)(lds + (wm * 64 + 32 + (l & 31)) * 256 + ko);
    bf16x8 b0 = *(const bf16x8*)(lds + 32768 + (wn * 64 +      (l & 31)) * 256 + ko);
    bf16x8 b1 = *(const bf16x8*)(lds + 32768 + (wn * 64 + 32 + (l & 31)) * 256 + ko);
    acc[0][0] = __builtin_amdgcn_mfma_f32_32x32x16_bf16(a0, b0, acc[0][0], 0, 0, 0);
    acc[0][1] = __builtin_amdgcn_mfma_f32_32x32x16_bf16(a0, b1, acc[0][1], 0, 0, 0);
    acc[1][0] = __builtin_amdgcn_mfma_f32_32x32x16_bf16(a1, b0, acc[1][0], 0, 0, 0);
    acc[1][1] = __builtin_amdgcn_mfma_f32_32x32x16_bf16(a1, b1, acc[1][1], 0, 0, 0);
  }
  __syncthreads();
  // bounce transpose into [128 c][136 r] u16 (272 B rows)
  #pragma unroll
  for(int mi = 0; mi < 2; ++mi)
    #pragma unroll
    for(int ni = 0; ni < 2; ++ni){
      int c = wn * 64 + ni * 32 + (l & 31);
      #pragma unroll
      for(int reg = 0; reg < 16; ++reg){
        int r = wm * 64 + mi * 32 + (reg & 3) + 8 * (reg >> 2) + 4 * (l >> 5);
        *(unsigned short*)(lds + c * 272 + r * 2) = f2b(acc[mi][ni][reg]);
      }
    }
  __syncthreads();
  #pragma unroll
  for(int q = 0; q < 8; ++q){
    int id = q * 256 + t;
    int c = id >> 4, xc = id & 15;
    u16x8 v = *(const u16x8*)(lds + c * 272 + xc * 16);
    *(u16x8*)((char*)Bt + (size_t)c * (NN * 2) + (size_t)r0 * 2 + xc * 16) = v;
  }
}

// ---------------- layer-0 B producer: A = bf16(feat0 * isd) ----------------
__global__ __launch_bounds__(256) void k_makeB(const float* __restrict__ feat,
                                               const float* __restrict__ isd,
                                               const unsigned short* __restrict__ Wt,
                                               unsigned short* __restrict__ Bt){
  __shared__ char lds[65536];
  const int t = threadIdx.x;
  const int r0 = blockIdx.x * 128;
  #pragma unroll
  for(int q = 0; q < 16; ++q){
    int idx4 = q * 256 + t;
    int r = idx4 >> 5, i4 = idx4 & 31;
    f32x4 v = ((const f32x4*)(feat + (size_t)(r0 + r) * HID))[i4];
    float sc = isd[r0 + r];
    u16x4 w;
    w[0] = f2b(v[0] * sc); w[1] = f2b(v[1] * sc);
    w[2] = f2b(v[2] * sc); w[3] = f2b(v[3] * sc);
    *(u16x4*)(lds + r * 256 + ((i4 * 8) ^ ((r & 7) << 4))) = w;
  }
  bcore(lds, Wt, Bt, r0, t);
}

// ------- fused: partial-reduce + norm + bias + softplus + next-layer A@W -> Bt -------
__global__ __launch_bounds__(256) void k_next(const float* __restrict__ partial,
                                              const float* __restrict__ isd,
                                              const void* __restrict__ bsv,
                                              int lyr, const int* __restrict__ flagp,
                                              const unsigned short* __restrict__ Wt,
                                              unsigned short* __restrict__ Bt){
  __shared__ char lds[65536];
  const int t = threadIdx.x;
  const int r0 = blockIdx.x * 128;
  const int mode = *flagp;
  #pragma unroll
  for(int q = 0; q < 16; ++q){
    int idx4 = q * 256 + t;
    int r = idx4 >> 5, i4 = idx4 & 31;
    f32x4 v;
    v[0] = 0.f; v[1] = 0.f; v[2] = 0.f; v[3] = 0.f;
    #pragma unroll
    for(int p = 0; p < 8; ++p){
      f32x4 u = *(const f32x4*)(partial + ((size_t)p << 20) + (size_t)(r0 + r) * HID + i4 * 4);
      v[0] += u[0]; v[1] += u[1]; v[2] += u[2]; v[3] += u[3];
    }
    float sc = isd[r0 + r];
    u16x4 w;
    #pragma unroll
    for(int j = 0; j < 4; ++j){
      int c = i4 * 4 + j;
      float b = mode ? b2f(((const unsigned short*)bsv)[lyr * 128 + c])
                     : ((const float*)bsv)[lyr * 128 + c];
      float h = v[j] * sc + b;
      float sp = fmaxf(h, 0.f) + log1pf(expf(-fabsf(h)));   // stable softplus
      w[j] = f2b(sp * sc);                                   // pre-scale for next layer
    }
    *(u16x4*)(lds + r * 256 + ((i4 * 8) ^ ((r & 7) << 4))) = w;
  }
  bcore(lds, Wt, Bt, r0, t);
}

// ---------------- main GEMM: partial[y] = adj[r0:r0+128, kwin] @ h2[kwin, :] ----
__global__ __launch_bounds__(256, 2) void k_gemm(const void* __restrict__ adj_in,
                                                 const unsigned short* __restrict__ adjb,
                                                 const unsigned short* __restrict__ Bt,
                                                 const int* __restrict__ flagp,
                                                 float* __restrict__ partial){
  __shared__ char lds[65536];                 // 2 bufs x (A 16KiB + B 16KiB), 128B rows
  const int t = threadIdx.x, wid = t >> 6, l = t & 63;
  const int r0 = blockIdx.x * 128;
  const int kbase = blockIdx.y * 1024;
  const unsigned short* A = (*flagp) ? (const unsigned short*)adj_in : adjb;

  auto stage = [&](int buf, int kt){
    const int bb = buf * 32768;
    #pragma unroll
    for(int q = 0; q < 4; ++q){               // A: 128 rows x 128B
      int ob = q * 4096 + wid * 1024;
      int o = ob + l * 16;
      int row = o >> 7, x = o & 127;
      gld_lds16((const char*)A + ((size_t)(r0 + row) * NN + kt) * 2 + (x ^ ((row & 7) << 4)),
                lds + bb + ob);
    }
    #pragma unroll
    for(int q = 0; q < 4; ++q){               // B: 128 cols x 128B
      int ob = q * 4096 + wid * 1024;
      int o = ob + l * 16;
      int c = o >> 7, x = o & 127;
      gld_lds16((const char*)Bt + ((size_t)c * NN + kt) * 2 + (x ^ ((c & 7) << 4)),
                lds + bb + 16384 + ob);
    }
  };

  const int wm = wid >> 1, wn = wid & 1;
  f32x16 acc[2][2];
  #pragma unroll
  for(int a = 0; a < 2; ++a)
    #pragma unroll
    for(int b = 0; b < 2; ++b)
      #pragma unroll
      for(int r2 = 0; r2 < 16; ++r2) acc[a][b][r2] = 0.f;

  const int rlo = l & 31;
  const int swz = (l & 7) << 4;
  const int khalf = (l >> 5) << 4;

  stage(0, kbase);
  for(int it = 0; it < 16; ++it){
    const int cur = it & 1;
    __syncthreads();
    if(it < 15) stage(cur ^ 1, kbase + (it + 1) * 64);
    const int bb = cur * 32768;
    #pragma unroll
    for(int kk = 0; kk < 4; ++kk){
      int ko = (kk * 32 + khalf) ^ swz;
      bf16x8 a0 = *(const bf16x8*)(lds + bb +         (wm * 64 + rlo)      * 128 + ko);
      bf16x8 a1 = *(const bf16x8*)(lds + bb +         (wm * 64 + rlo + 32) * 128 + ko);
      bf16x8 b0 = *(const bf16x8*)(lds + bb + 16384 + (wn * 64 + rlo)      * 128 + ko);
      bf16x8 b1 = *(const bf16x8*)(lds + bb + 16384 + (wn * 64 + rlo + 32) * 128 + ko);
      acc[0][0] = __builtin_amdgcn_mfma_f32_32x32x16_bf16(a0, b0, acc[0][0], 0, 0, 0);
      acc[0][1] = __builtin_amdgcn_mfma_f32_32x32x16_bf16(a0, b1, acc[0][1], 0, 0, 0);
      acc[1][0] = __builtin_amdgcn_mfma_f32_32x32x16_bf16(a1, b0, acc[1][0], 0, 0, 0);
      acc[1][1] = __builtin_amdgcn_mfma_f32_32x32x16_bf16(a1, b1, acc[1][1], 0, 0, 0);
    }
  }

  float* pp = partial + ((size_t)blockIdx.y << 20);
  #pragma unroll
  for(int mi = 0; mi < 2; ++mi)
    #pragma unroll
    for(int ni = 0; ni < 2; ++ni)
      #pragma unroll
      for(int reg = 0; reg < 16; ++reg){
        int r = r0 + wm * 64 + mi * 32 + (reg & 3) + 8 * (reg >> 2) + 4 * (l >> 5);
        int c = wn * 64 + ni * 32 + rlo;
        pp[(size_t)r * HID + c] = acc[mi][ni][reg];
      }
}

// ---------------- final: reduce + norm + bias + softplus -> out ----------------
__global__ __launch_bounds__(256) void k_out(const float* __restrict__ partial,
                                             const float* __restrict__ isd,
                                             const void* __restrict__ bsv,
                                             int lyr, const int* __restrict__ flagp,
                                             void* __restrict__ out){
  const int x = blockIdx.x * 256 + threadIdx.x;
  float v = 0.f;
  #pragma unroll
  for(int p = 0; p < 8; ++p) v += partial[((size_t)p << 20) + x];
  const int r = x >> 7, c = x & 127;
  const int mode = *flagp;
  float b = mode ? b2f(((const unsigned short*)bsv)[lyr * 128 + c])
                 : ((const float*)bsv)[lyr * 128 + c];
  v = v * isd[r] + b;
  float sp = fmaxf(v, 0.f) + log1pf(expf(-fabsf(v)));
  if(mode) ((unsigned short*)out)[x] = f2b(sp);
  else     ((float*)out)[x] = sp;
}

extern "C" void kernel_launch(void* const* d_in, const int* in_sizes, int n_in,
                              void* d_out, int out_size, void* d_ws, size_t ws_size,
                              hipStream_t stream){
  const void* pos = d_in[0];
  const void* emb = d_in[1];
  const void* adj = d_in[2];
  const void* Ws  = d_in[3];
  const void* bs  = d_in[4];

  // ws: flag @0 | isd @0x1000 | feat @0x10000 (4M) | Bt @0x410000 (2M)
  //     Wt @0x610000 (128K) | partial @0x630000 (32M) | adjb @0x2630000 (128M)
  char* ws = (char*)d_ws;
  int*            flag    = (int*)(ws);
  float*          isd     = (float*)(ws + 0x1000);
  float*          feat    = (float*)(ws + 0x10000);
  unsigned short* Bt      = (unsigned short*)(ws + 0x410000);
  unsigned short* Wt      = (unsigned short*)(ws + 0x610000);
  float*          partial = (float*)(ws + 0x630000);
  unsigned short* adjb    = (unsigned short*)(ws + 0x2630000);

  k_detect<<<1,    256, 0, stream>>>((const unsigned int*)adj, flag);
  k_degcvt<<<2048, 256, 0, stream>>>(adj, flag, isd, adjb);
  k_feat0 <<<4096, 256, 0, stream>>>(pos, emb, flag, feat);
  k_wt    <<<256,  256, 0, stream>>>(Ws, flag, Wt);

  k_makeB<<<64, 256, 0, stream>>>(feat, isd, Wt, Bt);
  k_gemm <<<dim3(64, 8), 256, 0, stream>>>(adj, adjb, Bt, flag, partial);
  for(int lyr = 1; lyr < 4; ++lyr){
    k_next<<<64, 256, 0, stream>>>(partial, isd, bs, lyr - 1, flag, Wt + lyr * 16384, Bt);
    k_gemm<<<dim3(64, 8), 256, 0, stream>>>(adj, adjb, Bt, flag, partial);
  }
  k_out<<<4096, 256, 0, stream>>>(partial, isd, bs, 3, flag, d_out);
}

// Round 4
// 329.387 us; speedup vs baseline: 1.5200x; 1.5200x over previous
//
#include <hip/hip_runtime.h>
#include <hip/hip_bf16.h>
#include <cstdint>

#define NN   8192
#define HID  128

typedef __attribute__((ext_vector_type(8)))  __bf16          bf16x8;
typedef __attribute__((ext_vector_type(16))) float           f32x16;
typedef __attribute__((ext_vector_type(8)))  unsigned short  u16x8;
typedef __attribute__((ext_vector_type(4)))  unsigned short  u16x4;
typedef __attribute__((ext_vector_type(4)))  float           f32x4;

__device__ __forceinline__ float b2f(unsigned short u){
  union { unsigned int i; float f; } v; v.i = ((unsigned int)u) << 16; return v.f;
}
__device__ __forceinline__ unsigned short f2b(float f){
  unsigned int i = __float_as_uint(f);
  unsigned int r = (i + 0x7FFFu + ((i >> 16) & 1u)) >> 16;   // RNE
  return (unsigned short)r;
}
__device__ __forceinline__ void gld_lds16(const void* g, void* l){
  __builtin_amdgcn_global_load_lds((const __attribute__((address_space(1))) unsigned int*)g,
                                   (__attribute__((address_space(3))) unsigned int*)l, 16, 0, 0);
}

// ---------------- dtype detect: bf16 buffers -> flag=1, f32 -> flag=0 ----------------
__global__ __launch_bounds__(256) void k_detect(const unsigned int* __restrict__ a,
                                                int* __restrict__ flag){
  __shared__ int cnt;
  if(threadIdx.x == 0) cnt = 0;
  __syncthreads();
  int c = 0;
  #pragma unroll
  for(int i = 0; i < 16; ++i){
    unsigned int w = a[i * 256 + threadIdx.x];
    c += (((w >> 8) & 0xC0u) == 0u) ? 1 : 0;
  }
  atomicAdd(&cnt, c);
  __syncthreads();
  if(threadIdx.x == 0) *flag = (cnt > 3000) ? 1 : 0;
}

// -------- deg + inv_sqrt_deg, fused f32->bf16 adj convert (one wave per row) --------
__global__ __launch_bounds__(256) void k_degcvt(const void* __restrict__ adjv,
                                                const int* __restrict__ flagp,
                                                float* __restrict__ isd,
                                                unsigned short* __restrict__ adjb){
  const int wid = threadIdx.x >> 6, l = threadIdx.x & 63;
  const int row = blockIdx.x * 4 + wid;
  float s = 0.f;
  if(*flagp){
    const u16x8* rp = (const u16x8*)((const unsigned short*)adjv + (size_t)row * NN);
    #pragma unroll
    for(int it = 0; it < 16; ++it){
      u16x8 v = rp[it * 64 + l];
      #pragma unroll
      for(int j = 0; j < 8; ++j) s += b2f(v[j]);
    }
  } else {
    const f32x4* rp = (const f32x4*)((const float*)adjv + (size_t)row * NN);
    u16x4* wp = (u16x4*)(adjb + (size_t)row * NN);
    #pragma unroll
    for(int it = 0; it < 32; ++it){
      f32x4 v = rp[it * 64 + l];
      s += v[0] + v[1] + v[2] + v[3];
      u16x4 w;
      w[0] = f2b(v[0]); w[1] = f2b(v[1]); w[2] = f2b(v[2]); w[3] = f2b(v[3]);
      wp[it * 64 + l] = w;
    }
  }
  #pragma unroll
  for(int m = 32; m > 0; m >>= 1) s += __shfl_xor(s, m, 64);
  if(l == 0) isd[row] = (s > 0.f) ? rsqrtf(fmaxf(s, 1e-12f)) : 0.f;
}

// ---------------- hA0 = bf16(concat(pos, emb) * isd) ----------------
__global__ __launch_bounds__(256) void k_hA0(const void* __restrict__ pos,
                                             const void* __restrict__ emb,
                                             const int* __restrict__ flagp,
                                             const float* __restrict__ isd,
                                             unsigned short* __restrict__ hA){
  const int x = blockIdx.x * 256 + threadIdx.x;
  const int r = x >> 7, c = x & 127;
  float v;
  if(*flagp){
    v = b2f(c < 3 ? ((const unsigned short*)pos)[r * 3 + c]
                  : ((const unsigned short*)emb)[r * 125 + (c - 3)]);
  } else {
    v = (c < 3) ? ((const float*)pos)[r * 3 + c]
                : ((const float*)emb)[r * 125 + (c - 3)];
  }
  hA[x] = f2b(v * isd[r]);
}

// ---------------- W transpose to bf16: Wt[l][c][i] = bf16(Ws[l][i][c]) ----------------
__global__ __launch_bounds__(256) void k_wt(const void* __restrict__ Ws,
                                            const int* __restrict__ flagp,
                                            unsigned short* __restrict__ Wt){
  const int x = blockIdx.x * 256 + threadIdx.x;
  const int lyr = x >> 14, rem = x & 16383, i = rem >> 7, c = rem & 127;
  unsigned short u;
  if(*flagp) u = ((const unsigned short*)Ws)[x];
  else       u = f2b(((const float*)Ws)[x]);
  Wt[lyr * 16384 + c * 128 + i] = u;
}

// ---- makeB: Bt[c][k] = (hA @ W)^T for a 128-row tile; hA already pre-scaled bf16 ----
__global__ __launch_bounds__(256) void k_makeB(const unsigned short* __restrict__ hA,
                                               const unsigned short* __restrict__ Wt,
                                               unsigned short* __restrict__ Bt){
  __shared__ char lds[65536];                 // [0,32K)=A, [32K,64K)=Wt, reuse for bounce
  const int t = threadIdx.x, wid = t >> 6, l = t & 63;
  const int r0 = blockIdx.x * 128;

  // stage A rows (256B each) from hA, pre-swizzled source
  #pragma unroll
  for(int q = 0; q < 8; ++q){
    int ob = q * 4096 + wid * 1024;
    int o  = ob + l * 16;
    int r  = o >> 8, x = o & 255;
    gld_lds16((const char*)hA + ((size_t)(r0 + r) << 8) + (x ^ ((r & 7) << 4)), lds + ob);
  }
  // stage Wt (256B rows), pre-swizzled source
  #pragma unroll
  for(int q = 0; q < 8; ++q){
    int ob = q * 4096 + wid * 1024;
    int o  = ob + l * 16;
    int c  = o >> 8, x = o & 255;
    gld_lds16((const char*)Wt + c * 256 + (x ^ ((c & 7) << 4)), lds + 32768 + ob);
  }
  __syncthreads();

  const int wm = wid >> 1, wn = wid & 1;
  f32x16 acc[2][2];
  #pragma unroll
  for(int a = 0; a < 2; ++a)
    #pragma unroll
    for(int b = 0; b < 2; ++b)
      #pragma unroll
      for(int r2 = 0; r2 < 16; ++r2) acc[a][b][r2] = 0.f;

  const int swz = (l & 7) << 4;
  #pragma unroll
  for(int st = 0; st < 8; ++st){
    int ko = (st * 32 + ((l >> 5) << 4)) ^ swz;
    bf16x8 a0 = *(const bf16x8*)(lds + (wm * 64 +      (l & 31)) * 256 + ko);
    bf16x8 a1 = *(const bf16x8*)(lds + (wm * 64 + 32 + (l & 31)) * 256 + ko);
    bf16x8 b0 = *(const bf16x8*)(lds + 32768 + (wn * 64 +      (l & 31)) * 256 + ko);
    bf16x8 b1 = *(const bf16x8*)(lds + 32768 + (wn * 64 + 32 + (l & 31)) * 256 + ko);
    acc[0][0] = __builtin_amdgcn_mfma_f32_32x32x16_bf16(a0, b0, acc[0][0], 0, 0, 0);
    acc[0][1] = __builtin_amdgcn_mfma_f32_32x32x16_bf16(a0, b1, acc[0][1], 0, 0, 0);
    acc[1][0] = __builtin_amdgcn_mfma_f32_32x32x16_bf16(a1, b0, acc[1][0], 0, 0, 0);
    acc[1][1] = __builtin_amdgcn_mfma_f32_32x32x16_bf16(a1, b1, acc[1][1], 0, 0, 0);
  }
  __syncthreads();
  // bounce transpose into [128 c][136 r] u16 (272 B rows)
  #pragma unroll
  for(int mi = 0; mi < 2; ++mi)
    #pragma unroll
    for(int ni = 0; ni < 2; ++ni){
      int c = wn * 64 + ni * 32 + (l & 31);
      #pragma unroll
      for(int reg = 0; reg < 16; ++reg){
        int r = wm * 64 + mi * 32 + (reg & 3) + 8 * (reg >> 2) + 4 * (l >> 5);
        *(unsigned short*)(lds + c * 272 + r * 2) = f2b(acc[mi][ni][reg]);
      }
    }
  __syncthreads();
  #pragma unroll
  for(int q = 0; q < 8; ++q){
    int id = q * 256 + t;
    int c = id >> 4, xc = id & 15;
    u16x8 v = *(const u16x8*)(lds + c * 272 + xc * 16);
    *(u16x8*)((char*)Bt + (size_t)c * (NN * 2) + (size_t)r0 * 2 + xc * 16) = v;
  }
}

// ------ main GEMM: BM=128, BN=128, BK=32, KSPLIT=16, 4 blocks/CU target ------
__global__ __launch_bounds__(256, 4) void k_gemm(const void* __restrict__ adj_in,
                                                 const unsigned short* __restrict__ adjb,
                                                 const unsigned short* __restrict__ Bt,
                                                 const int* __restrict__ flagp,
                                                 float* __restrict__ partial){
  __shared__ char lds[32768];                 // 2 bufs x (A 8KiB + B 8KiB), 64B rows
  const int t = threadIdx.x, wid = t >> 6, l = t & 63;
  const int r0 = blockIdx.x * 128;
  const int kbase = blockIdx.y * 512;
  const unsigned short* A = (*flagp) ? (const unsigned short*)adj_in : adjb;

  auto stage = [&](int buf, int kt){
    const int bb = buf * 16384;
    #pragma unroll
    for(int q = 0; q < 2; ++q){               // A: 128 rows x 64B
      int ob = q * 4096 + wid * 1024;
      int o = ob + l * 16;
      int row = o >> 6, x = o & 63;
      gld_lds16((const char*)A + ((size_t)(r0 + row) * NN + kt) * 2
                + (x ^ (((row >> 1) & 3) << 4)), lds + bb + ob);
    }
    #pragma unroll
    for(int q = 0; q < 2; ++q){               // B: 128 cols x 64B
      int ob = q * 4096 + wid * 1024;
      int o = ob + l * 16;
      int c = o >> 6, x = o & 63;
      gld_lds16((const char*)Bt + ((size_t)c * NN + kt) * 2
                + (x ^ (((c >> 1) & 3) << 4)), lds + bb + 8192 + ob);
    }
  };

  const int wm = wid >> 1, wn = wid & 1;
  f32x16 acc[2][2];
  #pragma unroll
  for(int a = 0; a < 2; ++a)
    #pragma unroll
    for(int b = 0; b < 2; ++b)
      #pragma unroll
      for(int r2 = 0; r2 < 16; ++r2) acc[a][b][r2] = 0.f;

  const int rlo = l & 31;
  const int swz = ((l >> 1) & 3) << 4;
  const int khalf = (l >> 5) << 4;

  stage(0, kbase);
  for(int it = 0; it < 16; ++it){
    const int cur = it & 1;
    __syncthreads();
    if(it < 15) stage(cur ^ 1, kbase + (it + 1) * 32);
    const int bb = cur * 16384;
    #pragma unroll
    for(int kk = 0; kk < 2; ++kk){
      int ko = (kk * 32 + khalf) ^ swz;
      bf16x8 a0 = *(const bf16x8*)(lds + bb +        (wm * 64 + rlo)      * 64 + ko);
      bf16x8 a1 = *(const bf16x8*)(lds + bb +        (wm * 64 + rlo + 32) * 64 + ko);
      bf16x8 b0 = *(const bf16x8*)(lds + bb + 8192 + (wn * 64 + rlo)      * 64 + ko);
      bf16x8 b1 = *(const bf16x8*)(lds + bb + 8192 + (wn * 64 + rlo + 32) * 64 + ko);
      acc[0][0] = __builtin_amdgcn_mfma_f32_32x32x16_bf16(a0, b0, acc[0][0], 0, 0, 0);
      acc[0][1] = __builtin_amdgcn_mfma_f32_32x32x16_bf16(a0, b1, acc[0][1], 0, 0, 0);
      acc[1][0] = __builtin_amdgcn_mfma_f32_32x32x16_bf16(a1, b0, acc[1][0], 0, 0, 0);
      acc[1][1] = __builtin_amdgcn_mfma_f32_32x32x16_bf16(a1, b1, acc[1][1], 0, 0, 0);
    }
  }

  float* pp = partial + ((size_t)blockIdx.y << 20);
  #pragma unroll
  for(int mi = 0; mi < 2; ++mi)
    #pragma unroll
    for(int ni = 0; ni < 2; ++ni)
      #pragma unroll
      for(int reg = 0; reg < 16; ++reg){
        int r = r0 + wm * 64 + mi * 32 + (reg & 3) + 8 * (reg >> 2) + 4 * (l >> 5);
        int c = wn * 64 + ni * 32 + rlo;
        pp[(size_t)r * HID + c] = acc[mi][ni][reg];
      }
}

// ------ epilogue (full grid): reduce 16 partials + norm + bias + softplus ------
template<bool LAST>
__global__ __launch_bounds__(256) void k_epi(const float* __restrict__ partial,
                                             const float* __restrict__ isd,
                                             const void* __restrict__ bsv,
                                             int lyr, const int* __restrict__ flagp,
                                             unsigned short* __restrict__ hA,
                                             void* __restrict__ out){
  const int x = blockIdx.x * 256 + threadIdx.x;
  float v = 0.f;
  #pragma unroll
  for(int p = 0; p < 16; ++p) v += partial[((size_t)p << 20) + x];
  const int r = x >> 7, c = x & 127;
  const int mode = *flagp;
  float b = mode ? b2f(((const unsigned short*)bsv)[lyr * 128 + c])
                 : ((const float*)bsv)[lyr * 128 + c];
  float sc = isd[r];
  v = v * sc + b;
  float sp = fmaxf(v, 0.f) + log1pf(expf(-fabsf(v)));   // stable softplus
  if(LAST){
    if(mode) ((unsigned short*)out)[x] = f2b(sp);
    else     ((float*)out)[x] = sp;
  } else {
    hA[x] = f2b(sp * sc);                                // pre-scale for next layer
  }
}

extern "C" void kernel_launch(void* const* d_in, const int* in_sizes, int n_in,
                              void* d_out, int out_size, void* d_ws, size_t ws_size,
                              hipStream_t stream){
  const void* pos = d_in[0];
  const void* emb = d_in[1];
  const void* adj = d_in[2];
  const void* Ws  = d_in[3];
  const void* bs  = d_in[4];

  // ws: flag@0 | isd@0x1000 | hA@0x10000 (2M) | Bt@0x210000 (2M)
  //     Wt@0x410000 (128K) | partial@0x430000 (64M) | adjb@0x4430000 (128M)
  char* ws = (char*)d_ws;
  int*            flag    = (int*)(ws);
  float*          isd     = (float*)(ws + 0x1000);
  unsigned short* hA      = (unsigned short*)(ws + 0x10000);
  unsigned short* Bt      = (unsigned short*)(ws + 0x210000);
  unsigned short* Wt      = (unsigned short*)(ws + 0x410000);
  float*          partial = (float*)(ws + 0x430000);
  unsigned short* adjb    = (unsigned short*)(ws + 0x4430000);

  k_detect<<<1,    256, 0, stream>>>((const unsigned int*)adj, flag);
  k_degcvt<<<2048, 256, 0, stream>>>(adj, flag, isd, adjb);
  k_hA0   <<<4096, 256, 0, stream>>>(pos, emb, flag, isd, hA);
  k_wt    <<<256,  256, 0, stream>>>(Ws, flag, Wt);

  for(int lyr = 0; lyr < 4; ++lyr){
    k_makeB<<<64, 256, 0, stream>>>(hA, Wt + lyr * 16384, Bt);
    k_gemm <<<dim3(64, 16), 256, 0, stream>>>(adj, adjb, Bt, flag, partial);
    if(lyr < 3) k_epi<false><<<4096, 256, 0, stream>>>(partial, isd, bs, lyr, flag, hA, nullptr);
    else        k_epi<true ><<<4096, 256, 0, stream>>>(partial, isd, bs, lyr, flag, nullptr, d_out);
  }
}

// Round 5
// 295.552 us; speedup vs baseline: 1.6941x; 1.1145x over previous
//
#include <hip/hip_runtime.h>
#include <hip/hip_bf16.h>
#include <cstdint>

#define NN   8192
#define HID  128

typedef __attribute__((ext_vector_type(8)))  __bf16          bf16x8;
typedef __attribute__((ext_vector_type(16))) float           f32x16;
typedef __attribute__((ext_vector_type(8)))  unsigned short  u16x8;
typedef __attribute__((ext_vector_type(4)))  unsigned short  u16x4;
typedef __attribute__((ext_vector_type(4)))  float           f32x4;

__device__ __forceinline__ float b2f(unsigned short u){
  union { unsigned int i; float f; } v; v.i = ((unsigned int)u) << 16; return v.f;
}
__device__ __forceinline__ unsigned short f2b(float f){
  unsigned int i = __float_as_uint(f);
  unsigned int r = (i + 0x7FFFu + ((i >> 16) & 1u)) >> 16;   // RNE
  return (unsigned short)r;
}
__device__ __forceinline__ void gld_lds16(const void* g, void* l){
  __builtin_amdgcn_global_load_lds((const __attribute__((address_space(1))) unsigned int*)g,
                                   (__attribute__((address_space(3))) unsigned int*)l, 16, 0, 0);
}

// ---------------- dtype detect: bf16 buffers -> flag=1, f32 -> flag=0 ----------------
__global__ __launch_bounds__(256) void k_detect(const unsigned int* __restrict__ a,
                                                int* __restrict__ flag){
  __shared__ int cnt;
  if(threadIdx.x == 0) cnt = 0;
  __syncthreads();
  int c = 0;
  #pragma unroll
  for(int i = 0; i < 16; ++i){
    unsigned int w = a[i * 256 + threadIdx.x];
    c += (((w >> 8) & 0xC0u) == 0u) ? 1 : 0;
  }
  atomicAdd(&cnt, c);
  __syncthreads();
  if(threadIdx.x == 0) *flag = (cnt > 3000) ? 1 : 0;
}

// -------- deg + inv_sqrt_deg, fused f32->bf16 adj convert (one wave per row) --------
__global__ __launch_bounds__(256) void k_degcvt(const void* __restrict__ adjv,
                                                const int* __restrict__ flagp,
                                                float* __restrict__ isd,
                                                unsigned short* __restrict__ adjb){
  const int wid = threadIdx.x >> 6, l = threadIdx.x & 63;
  const int row = blockIdx.x * 4 + wid;
  float s = 0.f;
  if(*flagp){
    const u16x8* rp = (const u16x8*)((const unsigned short*)adjv + (size_t)row * NN);
    #pragma unroll
    for(int it = 0; it < 16; ++it){
      u16x8 v = rp[it * 64 + l];
      #pragma unroll
      for(int j = 0; j < 8; ++j) s += b2f(v[j]);
    }
  } else {
    const f32x4* rp = (const f32x4*)((const float*)adjv + (size_t)row * NN);
    u16x4* wp = (u16x4*)(adjb + (size_t)row * NN);
    #pragma unroll
    for(int it = 0; it < 32; ++it){
      f32x4 v = rp[it * 64 + l];
      s += v[0] + v[1] + v[2] + v[3];
      u16x4 w;
      w[0] = f2b(v[0]); w[1] = f2b(v[1]); w[2] = f2b(v[2]); w[3] = f2b(v[3]);
      wp[it * 64 + l] = w;
    }
  }
  #pragma unroll
  for(int m = 32; m > 0; m >>= 1) s += __shfl_xor(s, m, 64);
  if(l == 0) isd[row] = (s > 0.f) ? rsqrtf(fmaxf(s, 1e-12f)) : 0.f;
}

// ---------------- hA0 = bf16(concat(pos, emb) * isd) ----------------
__global__ __launch_bounds__(256) void k_hA0(const void* __restrict__ pos,
                                             const void* __restrict__ emb,
                                             const int* __restrict__ flagp,
                                             const float* __restrict__ isd,
                                             unsigned short* __restrict__ hA){
  const int x = blockIdx.x * 256 + threadIdx.x;
  const int r = x >> 7, c = x & 127;
  float v;
  if(*flagp){
    v = b2f(c < 3 ? ((const unsigned short*)pos)[r * 3 + c]
                  : ((const unsigned short*)emb)[r * 125 + (c - 3)]);
  } else {
    v = (c < 3) ? ((const float*)pos)[r * 3 + c]
                : ((const float*)emb)[r * 125 + (c - 3)];
  }
  hA[x] = f2b(v * isd[r]);
}

// ---------------- W transpose to bf16: Wt[l][c][i] = bf16(Ws[l][i][c]) ----------------
__global__ __launch_bounds__(256) void k_wt(const void* __restrict__ Ws,
                                            const int* __restrict__ flagp,
                                            unsigned short* __restrict__ Wt){
  const int x = blockIdx.x * 256 + threadIdx.x;
  const int lyr = x >> 14, rem = x & 16383, i = rem >> 7, c = rem & 127;
  unsigned short u;
  if(*flagp) u = ((const unsigned short*)Ws)[x];
  else       u = f2b(((const float*)Ws)[x]);
  Wt[lyr * 16384 + c * 128 + i] = u;
}

// ---- makeB: Bt[c][k] = (hA @ W)^T for a 64-row tile; hA pre-scaled bf16 ----
__global__ __launch_bounds__(256) void k_makeB(const unsigned short* __restrict__ hA,
                                               const unsigned short* __restrict__ Wt,
                                               unsigned short* __restrict__ Bt){
  __shared__ char lds[49152];                 // A [0,16K), Wt [16K,48K); bounce reuses [0,18.4K)
  const int t = threadIdx.x, wid = t >> 6, l = t & 63;
  const int r0 = blockIdx.x * 64;

  // stage A rows (64 x 256B), pre-swizzled source
  #pragma unroll
  for(int q = 0; q < 4; ++q){
    int ob = q * 4096 + wid * 1024;
    int o  = ob + l * 16;
    int r  = o >> 8, x = o & 255;
    gld_lds16((const char*)hA + ((size_t)(r0 + r) << 8) + (x ^ ((r & 7) << 4)), lds + ob);
  }
  // stage Wt (128 x 256B), pre-swizzled source
  #pragma unroll
  for(int q = 0; q < 8; ++q){
    int ob = q * 4096 + wid * 1024;
    int o  = ob + l * 16;
    int c  = o >> 8, x = o & 255;
    gld_lds16((const char*)Wt + c * 256 + (x ^ ((c & 7) << 4)), lds + 16384 + ob);
  }
  __syncthreads();

  const int wm = wid >> 1, wn = wid & 1;      // wave tile: 32 rows x 64 cols
  f32x16 acc[2];
  #pragma unroll
  for(int b = 0; b < 2; ++b)
    #pragma unroll
    for(int r2 = 0; r2 < 16; ++r2) acc[b][r2] = 0.f;

  const int rlo = l & 31;
  const int swz = (l & 7) << 4;
  #pragma unroll
  for(int s = 0; s < 8; ++s){
    int ko = (s * 32 + ((l >> 5) << 4)) ^ swz;
    bf16x8 a  = *(const bf16x8*)(lds + (wm * 32 + rlo) * 256 + ko);
    bf16x8 b0 = *(const bf16x8*)(lds + 16384 + (wn * 64 +      rlo) * 256 + ko);
    bf16x8 b1 = *(const bf16x8*)(lds + 16384 + (wn * 64 + 32 + rlo) * 256 + ko);
    acc[0] = __builtin_amdgcn_mfma_f32_32x32x16_bf16(a, b0, acc[0], 0, 0, 0);
    acc[1] = __builtin_amdgcn_mfma_f32_32x32x16_bf16(a, b1, acc[1], 0, 0, 0);
  }
  __syncthreads();
  // bounce transpose into [128 c][72 r] u16 (144 B rows, 16B-aligned)
  #pragma unroll
  for(int ni = 0; ni < 2; ++ni){
    int c = wn * 64 + ni * 32 + rlo;
    #pragma unroll
    for(int reg = 0; reg < 16; ++reg){
      int r = wm * 32 + (reg & 3) + 8 * (reg >> 2) + 4 * (l >> 5);
      *(unsigned short*)(lds + c * 144 + r * 2) = f2b(acc[ni][reg]);
    }
  }
  __syncthreads();
  // write 128 c x 64 r: 1024 chunks of 16B
  #pragma unroll
  for(int q = 0; q < 4; ++q){
    int id = q * 256 + t;
    int c = id >> 3, xc = id & 7;
    u16x8 v = *(const u16x8*)(lds + c * 144 + xc * 16);
    *(u16x8*)((char*)Bt + (size_t)c * (NN * 2) + (size_t)r0 * 2 + xc * 16) = v;
  }
}

// ------ main GEMM: BM=64, BN=128, BK=32, KSPLIT=8, 4 blocks/CU ------
__global__ __launch_bounds__(256, 4) void k_gemm(const void* __restrict__ adj_in,
                                                 const unsigned short* __restrict__ adjb,
                                                 const unsigned short* __restrict__ Bt,
                                                 const int* __restrict__ flagp,
                                                 float* __restrict__ partial){
  __shared__ char lds[24576];                 // 2 bufs x (A 4KiB + B 8KiB), 64B rows
  const int t = threadIdx.x, wid = t >> 6, l = t & 63;
  const int r0 = blockIdx.x * 64;
  const int kbase = blockIdx.y * 1024;
  const unsigned short* A = (*flagp) ? (const unsigned short*)adj_in : adjb;

  auto stage = [&](int buf, int kt){
    const int bb = buf * 12288;
    {                                         // A: 64 rows x 64B (one chunk/thread)
      int ob = wid * 1024;
      int o = ob + l * 16;
      int row = o >> 6, x = o & 63;
      gld_lds16((const char*)A + ((size_t)(r0 + row) * NN + kt) * 2
                + (x ^ (((row >> 1) & 3) << 4)), lds + bb + ob);
    }
    #pragma unroll
    for(int q = 0; q < 2; ++q){               // B: 128 cols x 64B
      int ob = q * 4096 + wid * 1024;
      int o = ob + l * 16;
      int c = o >> 6, x = o & 63;
      gld_lds16((const char*)Bt + ((size_t)c * NN + kt) * 2
                + (x ^ (((c >> 1) & 3) << 4)), lds + bb + 4096 + ob);
    }
  };

  const int wm = wid >> 1, wn = wid & 1;      // wave tile: 32 rows x 64 cols
  f32x16 acc[2];
  #pragma unroll
  for(int b = 0; b < 2; ++b)
    #pragma unroll
    for(int r2 = 0; r2 < 16; ++r2) acc[b][r2] = 0.f;

  const int rlo = l & 31;
  const int swz = ((l >> 1) & 3) << 4;
  const int khalf = (l >> 5) << 4;

  stage(0, kbase);
  for(int it = 0; it < 32; ++it){
    const int cur = it & 1;
    __syncthreads();
    if(it < 31) stage(cur ^ 1, kbase + (it + 1) * 32);
    const int bb = cur * 12288;
    #pragma unroll
    for(int kk = 0; kk < 2; ++kk){
      int ko = (kk * 32 + khalf) ^ swz;
      bf16x8 a  = *(const bf16x8*)(lds + bb +        (wm * 32 + rlo)      * 64 + ko);
      bf16x8 b0 = *(const bf16x8*)(lds + bb + 4096 + (wn * 64 + rlo)      * 64 + ko);
      bf16x8 b1 = *(const bf16x8*)(lds + bb + 4096 + (wn * 64 + rlo + 32) * 64 + ko);
      acc[0] = __builtin_amdgcn_mfma_f32_32x32x16_bf16(a, b0, acc[0], 0, 0, 0);
      acc[1] = __builtin_amdgcn_mfma_f32_32x32x16_bf16(a, b1, acc[1], 0, 0, 0);
    }
  }

  float* pp = partial + ((size_t)blockIdx.y << 20);
  #pragma unroll
  for(int ni = 0; ni < 2; ++ni)
    #pragma unroll
    for(int reg = 0; reg < 16; ++reg){
      int r = r0 + wm * 32 + (reg & 3) + 8 * (reg >> 2) + 4 * (l >> 5);
      int c = wn * 64 + ni * 32 + rlo;
      pp[(size_t)r * HID + c] = acc[ni][reg];
    }
}

// ------ epilogue (full grid): reduce 8 partials + norm + bias + softplus ------
template<bool LAST>
__global__ __launch_bounds__(256) void k_epi(const float* __restrict__ partial,
                                             const float* __restrict__ isd,
                                             const void* __restrict__ bsv,
                                             int lyr, const int* __restrict__ flagp,
                                             unsigned short* __restrict__ hA,
                                             void* __restrict__ out){
  const int x = blockIdx.x * 256 + threadIdx.x;
  float v = 0.f;
  #pragma unroll
  for(int p = 0; p < 8; ++p) v += partial[((size_t)p << 20) + x];
  const int r = x >> 7, c = x & 127;
  const int mode = *flagp;
  float b = mode ? b2f(((const unsigned short*)bsv)[lyr * 128 + c])
                 : ((const float*)bsv)[lyr * 128 + c];
  float sc = isd[r];
  v = v * sc + b;
  float sp = fmaxf(v, 0.f) + log1pf(expf(-fabsf(v)));   // stable softplus
  if(LAST){
    if(mode) ((unsigned short*)out)[x] = f2b(sp);
    else     ((float*)out)[x] = sp;
  } else {
    hA[x] = f2b(sp * sc);                                // pre-scale for next layer
  }
}

extern "C" void kernel_launch(void* const* d_in, const int* in_sizes, int n_in,
                              void* d_out, int out_size, void* d_ws, size_t ws_size,
                              hipStream_t stream){
  const void* pos = d_in[0];
  const void* emb = d_in[1];
  const void* adj = d_in[2];
  const void* Ws  = d_in[3];
  const void* bs  = d_in[4];

  // ws: flag@0 | isd@0x1000 | hA@0x10000 (2M) | Bt@0x210000 (2M)
  //     Wt@0x410000 (128K) | partial@0x430000 (32M) | adjb@0x2430000 (128M)
  char* ws = (char*)d_ws;
  int*            flag    = (int*)(ws);
  float*          isd     = (float*)(ws + 0x1000);
  unsigned short* hA      = (unsigned short*)(ws + 0x10000);
  unsigned short* Bt      = (unsigned short*)(ws + 0x210000);
  unsigned short* Wt      = (unsigned short*)(ws + 0x410000);
  float*          partial = (float*)(ws + 0x430000);
  unsigned short* adjb    = (unsigned short*)(ws + 0x2430000);

  k_detect<<<1,    256, 0, stream>>>((const unsigned int*)adj, flag);
  k_degcvt<<<2048, 256, 0, stream>>>(adj, flag, isd, adjb);
  k_hA0   <<<4096, 256, 0, stream>>>(pos, emb, flag, isd, hA);
  k_wt    <<<256,  256, 0, stream>>>(Ws, flag, Wt);

  for(int lyr = 0; lyr < 4; ++lyr){
    k_makeB<<<128, 256, 0, stream>>>(hA, Wt + lyr * 16384, Bt);
    k_gemm <<<dim3(128, 8), 256, 0, stream>>>(adj, adjb, Bt, flag, partial);
    if(lyr < 3) k_epi<false><<<4096, 256, 0, stream>>>(partial, isd, bs, lyr, flag, hA, nullptr);
    else        k_epi<true ><<<4096, 256, 0, stream>>>(partial, isd, bs, lyr, flag, nullptr, d_out);
  }
}

// Round 6
// 282.285 us; speedup vs baseline: 1.7737x; 1.0470x over previous
//
#include <hip/hip_runtime.h>
#include <hip/hip_bf16.h>
#include <cstdint>

#define NN   8192
#define HID  128

typedef __attribute__((ext_vector_type(8)))  __bf16          bf16x8;
typedef __attribute__((ext_vector_type(16))) float           f32x16;
typedef __attribute__((ext_vector_type(8)))  unsigned short  u16x8;
typedef __attribute__((ext_vector_type(4)))  unsigned short  u16x4;
typedef __attribute__((ext_vector_type(4)))  float           f32x4;

__device__ __forceinline__ float b2f(unsigned short u){
  union { unsigned int i; float f; } v; v.i = ((unsigned int)u) << 16; return v.f;
}
__device__ __forceinline__ unsigned short f2b(float f){
  unsigned int i = __float_as_uint(f);
  unsigned int r = (i + 0x7FFFu + ((i >> 16) & 1u)) >> 16;   // RNE
  return (unsigned short)r;
}
__device__ __forceinline__ void gld_lds16(const void* g, void* l){
  __builtin_amdgcn_global_load_lds((const __attribute__((address_space(1))) unsigned int*)g,
                                   (__attribute__((address_space(3))) unsigned int*)l, 16, 0, 0);
}

// ---------------- dtype detect: bf16 buffers -> flag=1, f32 -> flag=0 ----------------
__global__ __launch_bounds__(256) void k_detect(const unsigned int* __restrict__ a,
                                                int* __restrict__ flag){
  __shared__ int cnt;
  if(threadIdx.x == 0) cnt = 0;
  __syncthreads();
  int c = 0;
  #pragma unroll
  for(int i = 0; i < 16; ++i){
    unsigned int w = a[i * 256 + threadIdx.x];
    c += (((w >> 8) & 0xC0u) == 0u) ? 1 : 0;
  }
  atomicAdd(&cnt, c);
  __syncthreads();
  if(threadIdx.x == 0) *flag = (cnt > 3000) ? 1 : 0;
}

// -------- deg + inv_sqrt_deg, fused f32->bf16 adj convert (one wave per row) --------
__global__ __launch_bounds__(256) void k_degcvt(const void* __restrict__ adjv,
                                                const int* __restrict__ flagp,
                                                float* __restrict__ isd,
                                                unsigned short* __restrict__ adjb){
  const int wid = threadIdx.x >> 6, l = threadIdx.x & 63;
  const int row = blockIdx.x * 4 + wid;
  float s = 0.f;
  if(*flagp){
    const u16x8* rp = (const u16x8*)((const unsigned short*)adjv + (size_t)row * NN);
    #pragma unroll
    for(int it = 0; it < 16; ++it){
      u16x8 v = rp[it * 64 + l];
      #pragma unroll
      for(int j = 0; j < 8; ++j) s += b2f(v[j]);
    }
  } else {
    const f32x4* rp = (const f32x4*)((const float*)adjv + (size_t)row * NN);
    u16x4* wp = (u16x4*)(adjb + (size_t)row * NN);
    #pragma unroll
    for(int it = 0; it < 32; ++it){
      f32x4 v = rp[it * 64 + l];
      s += v[0] + v[1] + v[2] + v[3];
      u16x4 w;
      w[0] = f2b(v[0]); w[1] = f2b(v[1]); w[2] = f2b(v[2]); w[3] = f2b(v[3]);
      wp[it * 64 + l] = w;
    }
  }
  #pragma unroll
  for(int m = 32; m > 0; m >>= 1) s += __shfl_xor(s, m, 64);
  if(l == 0) isd[row] = (s > 0.f) ? rsqrtf(fmaxf(s, 1e-12f)) : 0.f;
}

// ---------------- hA0 = bf16(concat(pos, emb) * isd) ----------------
__global__ __launch_bounds__(256) void k_hA0(const void* __restrict__ pos,
                                             const void* __restrict__ emb,
                                             const int* __restrict__ flagp,
                                             const float* __restrict__ isd,
                                             unsigned short* __restrict__ hA){
  const int x = blockIdx.x * 256 + threadIdx.x;
  const int r = x >> 7, c = x & 127;
  float v;
  if(*flagp){
    v = b2f(c < 3 ? ((const unsigned short*)pos)[r * 3 + c]
                  : ((const unsigned short*)emb)[r * 125 + (c - 3)]);
  } else {
    v = (c < 3) ? ((const float*)pos)[r * 3 + c]
                : ((const float*)emb)[r * 125 + (c - 3)];
  }
  hA[x] = f2b(v * isd[r]);
}

// ---------------- W transpose to bf16: Wt[l][c][i] = bf16(Ws[l][i][c]) ----------------
__global__ __launch_bounds__(256) void k_wt(const void* __restrict__ Ws,
                                            const int* __restrict__ flagp,
                                            unsigned short* __restrict__ Wt){
  const int x = blockIdx.x * 256 + threadIdx.x;
  const int lyr = x >> 14, rem = x & 16383, i = rem >> 7, c = rem & 127;
  unsigned short u;
  if(*flagp) u = ((const unsigned short*)Ws)[x];
  else       u = f2b(((const float*)Ws)[x]);
  Wt[lyr * 16384 + c * 128 + i] = u;
}

// ---- makeB: Bt[c][k] = (hA @ W)^T for a 64-row tile; hA pre-scaled bf16 ----
__global__ __launch_bounds__(256) void k_makeB(const unsigned short* __restrict__ hA,
                                               const unsigned short* __restrict__ Wt,
                                               unsigned short* __restrict__ Bt){
  __shared__ char lds[49152];                 // A [0,16K), Wt [16K,48K); bounce reuses [0,18.4K)
  const int t = threadIdx.x, wid = t >> 6, l = t & 63;
  const int r0 = blockIdx.x * 64;

  // stage A rows (64 x 256B), pre-swizzled source
  #pragma unroll
  for(int q = 0; q < 4; ++q){
    int ob = q * 4096 + wid * 1024;
    int o  = ob + l * 16;
    int r  = o >> 8, x = o & 255;
    gld_lds16((const char*)hA + ((size_t)(r0 + r) << 8) + (x ^ ((r & 7) << 4)), lds + ob);
  }
  // stage Wt (128 x 256B), pre-swizzled source
  #pragma unroll
  for(int q = 0; q < 8; ++q){
    int ob = q * 4096 + wid * 1024;
    int o  = ob + l * 16;
    int c  = o >> 8, x = o & 255;
    gld_lds16((const char*)Wt + c * 256 + (x ^ ((c & 7) << 4)), lds + 16384 + ob);
  }
  __syncthreads();

  const int wm = wid >> 1, wn = wid & 1;      // wave tile: 32 rows x 64 cols
  f32x16 acc[2];
  #pragma unroll
  for(int b = 0; b < 2; ++b)
    #pragma unroll
    for(int r2 = 0; r2 < 16; ++r2) acc[b][r2] = 0.f;

  const int rlo = l & 31;
  const int swz = (l & 7) << 4;
  #pragma unroll
  for(int s = 0; s < 8; ++s){
    int ko = (s * 32 + ((l >> 5) << 4)) ^ swz;
    bf16x8 a  = *(const bf16x8*)(lds + (wm * 32 + rlo) * 256 + ko);
    bf16x8 b0 = *(const bf16x8*)(lds + 16384 + (wn * 64 +      rlo) * 256 + ko);
    bf16x8 b1 = *(const bf16x8*)(lds + 16384 + (wn * 64 + 32 + rlo) * 256 + ko);
    acc[0] = __builtin_amdgcn_mfma_f32_32x32x16_bf16(a, b0, acc[0], 0, 0, 0);
    acc[1] = __builtin_amdgcn_mfma_f32_32x32x16_bf16(a, b1, acc[1], 0, 0, 0);
  }
  __syncthreads();
  // bounce transpose into [128 c][72 r] u16 (144 B rows, 16B-aligned)
  #pragma unroll
  for(int ni = 0; ni < 2; ++ni){
    int c = wn * 64 + ni * 32 + rlo;
    #pragma unroll
    for(int reg = 0; reg < 16; ++reg){
      int r = wm * 32 + (reg & 3) + 8 * (reg >> 2) + 4 * (l >> 5);
      *(unsigned short*)(lds + c * 144 + r * 2) = f2b(acc[ni][reg]);
    }
  }
  __syncthreads();
  // write 128 c x 64 r: 1024 chunks of 16B
  #pragma unroll
  for(int q = 0; q < 4; ++q){
    int id = q * 256 + t;
    int c = id >> 3, xc = id & 7;
    u16x8 v = *(const u16x8*)(lds + c * 144 + xc * 16);
    *(u16x8*)((char*)Bt + (size_t)c * (NN * 2) + (size_t)r0 * 2 + xc * 16) = v;
  }
}

// ------ main GEMM: BM=256, BN=128, BK=32, 8 waves (64x64 wave tile), KSPLIT=8 ------
__global__ __launch_bounds__(512, 4) void k_gemm(const void* __restrict__ adj_in,
                                                 const unsigned short* __restrict__ adjb,
                                                 const unsigned short* __restrict__ Bt,
                                                 const int* __restrict__ flagp,
                                                 float* __restrict__ partial){
  __shared__ char lds[49152];                 // 2 bufs x (A 16KiB + B 8KiB), 64B rows
  const int t = threadIdx.x, wid = t >> 6, l = t & 63;
  const int r0 = blockIdx.x * 256;
  const int kbase = blockIdx.y * 1024;
  const unsigned short* A = (*flagp) ? (const unsigned short*)adj_in : adjb;

  auto stage = [&](int buf, int kt){
    const int bb = buf * 24576;
    #pragma unroll
    for(int q = 0; q < 2; ++q){               // A: 256 rows x 64B (2 chunks/thread)
      int ob = q * 8192 + wid * 1024;
      int o = ob + l * 16;
      int row = o >> 6, x = o & 63;
      gld_lds16((const char*)A + ((size_t)(r0 + row) * NN + kt) * 2
                + (x ^ (((row >> 1) & 3) << 4)), lds + bb + ob);
    }
    {                                         // B: 128 cols x 64B (1 chunk/thread)
      int ob = wid * 1024;
      int o = ob + l * 16;
      int c = o >> 6, x = o & 63;
      gld_lds16((const char*)Bt + ((size_t)c * NN + kt) * 2
                + (x ^ (((c >> 1) & 3) << 4)), lds + bb + 16384 + ob);
    }
  };

  const int wr = wid >> 1, wc = wid & 1;      // wave tile: 64 rows x 64 cols
  f32x16 acc[2][2];
  #pragma unroll
  for(int a = 0; a < 2; ++a)
    #pragma unroll
    for(int b = 0; b < 2; ++b)
      #pragma unroll
      for(int r2 = 0; r2 < 16; ++r2) acc[a][b][r2] = 0.f;

  const int rlo = l & 31;
  const int swz = ((l >> 1) & 3) << 4;
  const int khalf = (l >> 5) << 4;

  stage(0, kbase);
  for(int it = 0; it < 32; ++it){
    const int cur = it & 1;
    __syncthreads();
    if(it < 31) stage(cur ^ 1, kbase + (it + 1) * 32);
    const int bb = cur * 24576;
    #pragma unroll
    for(int kk = 0; kk < 2; ++kk){
      int ko = (kk * 32 + khalf) ^ swz;
      bf16x8 a0 = *(const bf16x8*)(lds + bb +         (wr * 64 + rlo)      * 64 + ko);
      bf16x8 a1 = *(const bf16x8*)(lds + bb +         (wr * 64 + rlo + 32) * 64 + ko);
      bf16x8 b0 = *(const bf16x8*)(lds + bb + 16384 + (wc * 64 + rlo)      * 64 + ko);
      bf16x8 b1 = *(const bf16x8*)(lds + bb + 16384 + (wc * 64 + rlo + 32) * 64 + ko);
      acc[0][0] = __builtin_amdgcn_mfma_f32_32x32x16_bf16(a0, b0, acc[0][0], 0, 0, 0);
      acc[0][1] = __builtin_amdgcn_mfma_f32_32x32x16_bf16(a0, b1, acc[0][1], 0, 0, 0);
      acc[1][0] = __builtin_amdgcn_mfma_f32_32x32x16_bf16(a1, b0, acc[1][0], 0, 0, 0);
      acc[1][1] = __builtin_amdgcn_mfma_f32_32x32x16_bf16(a1, b1, acc[1][1], 0, 0, 0);
    }
  }

  float* pp = partial + ((size_t)blockIdx.y << 20);
  #pragma unroll
  for(int mi = 0; mi < 2; ++mi)
    #pragma unroll
    for(int ni = 0; ni < 2; ++ni)
      #pragma unroll
      for(int reg = 0; reg < 16; ++reg){
        int r = r0 + wr * 64 + mi * 32 + (reg & 3) + 8 * (reg >> 2) + 4 * (l >> 5);
        int c = wc * 64 + ni * 32 + rlo;
        pp[(size_t)r * HID + c] = acc[mi][ni][reg];
      }
}

// ------ epilogue (full grid): reduce 8 partials + norm + bias + softplus ------
template<bool LAST>
__global__ __launch_bounds__(256) void k_epi(const float* __restrict__ partial,
                                             const float* __restrict__ isd,
                                             const void* __restrict__ bsv,
                                             int lyr, const int* __restrict__ flagp,
                                             unsigned short* __restrict__ hA,
                                             void* __restrict__ out){
  const int x = blockIdx.x * 256 + threadIdx.x;
  float v = 0.f;
  #pragma unroll
  for(int p = 0; p < 8; ++p) v += partial[((size_t)p << 20) + x];
  const int r = x >> 7, c = x & 127;
  const int mode = *flagp;
  float b = mode ? b2f(((const unsigned short*)bsv)[lyr * 128 + c])
                 : ((const float*)bsv)[lyr * 128 + c];
  float sc = isd[r];
  v = v * sc + b;
  float sp = fmaxf(v, 0.f) + log1pf(expf(-fabsf(v)));   // stable softplus
  if(LAST){
    if(mode) ((unsigned short*)out)[x] = f2b(sp);
    else     ((float*)out)[x] = sp;
  } else {
    hA[x] = f2b(sp * sc);                                // pre-scale for next layer
  }
}

extern "C" void kernel_launch(void* const* d_in, const int* in_sizes, int n_in,
                              void* d_out, int out_size, void* d_ws, size_t ws_size,
                              hipStream_t stream){
  const void* pos = d_in[0];
  const void* emb = d_in[1];
  const void* adj = d_in[2];
  const void* Ws  = d_in[3];
  const void* bs  = d_in[4];

  // ws: flag@0 | isd@0x1000 | hA@0x10000 (2M) | Bt@0x210000 (2M)
  //     Wt@0x410000 (128K) | partial@0x430000 (32M) | adjb@0x2430000 (128M)
  char* ws = (char*)d_ws;
  int*            flag    = (int*)(ws);
  float*          isd     = (float*)(ws + 0x1000);
  unsigned short* hA      = (unsigned short*)(ws + 0x10000);
  unsigned short* Bt      = (unsigned short*)(ws + 0x210000);
  unsigned short* Wt      = (unsigned short*)(ws + 0x410000);
  float*          partial = (float*)(ws + 0x430000);
  unsigned short* adjb    = (unsigned short*)(ws + 0x2430000);

  k_detect<<<1,    256, 0, stream>>>((const unsigned int*)adj, flag);
  k_degcvt<<<2048, 256, 0, stream>>>(adj, flag, isd, adjb);
  k_hA0   <<<4096, 256, 0, stream>>>(pos, emb, flag, isd, hA);
  k_wt    <<<256,  256, 0, stream>>>(Ws, flag, Wt);

  for(int lyr = 0; lyr < 4; ++lyr){
    k_makeB<<<128, 256, 0, stream>>>(hA, Wt + lyr * 16384, Bt);
    k_gemm <<<dim3(32, 8), 512, 0, stream>>>(adj, adjb, Bt, flag, partial);
    if(lyr < 3) k_epi<false><<<4096, 256, 0, stream>>>(partial, isd, bs, lyr, flag, hA, nullptr);
    else        k_epi<true ><<<4096, 256, 0, stream>>>(partial, isd, bs, lyr, flag, nullptr, d_out);
  }
}

// Round 7
// 257.794 us; speedup vs baseline: 1.9422x; 1.0950x over previous
//
#include <hip/hip_runtime.h>
#include <hip/hip_bf16.h>
#include <cstdint>

#define NN   8192
#define HID  128

typedef __attribute__((ext_vector_type(8)))  __bf16          bf16x8;
typedef __attribute__((ext_vector_type(16))) float           f32x16;
typedef __attribute__((ext_vector_type(8)))  unsigned short  u16x8;
typedef __attribute__((ext_vector_type(4)))  unsigned short  u16x4;
typedef __attribute__((ext_vector_type(4)))  float           f32x4;

__device__ __forceinline__ float b2f(unsigned short u){
  union { unsigned int i; float f; } v; v.i = ((unsigned int)u) << 16; return v.f;
}
__device__ __forceinline__ unsigned short f2b(float f){
  unsigned int i = __float_as_uint(f);
  unsigned int r = (i + 0x7FFFu + ((i >> 16) & 1u)) >> 16;   // RNE
  return (unsigned short)r;
}
__device__ __forceinline__ void gld_lds16(const void* g, void* l){
  __builtin_amdgcn_global_load_lds((const __attribute__((address_space(1))) unsigned int*)g,
                                   (__attribute__((address_space(3))) unsigned int*)l, 16, 0, 0);
}

// ---------------- dtype detect: bf16 buffers -> flag=1, f32 -> flag=0 ----------------
__global__ __launch_bounds__(256) void k_detect(const unsigned int* __restrict__ a,
                                                int* __restrict__ flag){
  __shared__ int cnt;
  if(threadIdx.x == 0) cnt = 0;
  __syncthreads();
  int c = 0;
  #pragma unroll
  for(int i = 0; i < 16; ++i){
    unsigned int w = a[i * 256 + threadIdx.x];
    c += (((w >> 8) & 0xC0u) == 0u) ? 1 : 0;
  }
  atomicAdd(&cnt, c);
  __syncthreads();
  if(threadIdx.x == 0) *flag = (cnt > 3000) ? 1 : 0;
}

// -------- deg + inv_sqrt_deg, fused f32->bf16 adj convert (one wave per row) --------
__global__ __launch_bounds__(256) void k_degcvt(const void* __restrict__ adjv,
                                                const int* __restrict__ flagp,
                                                float* __restrict__ isd,
                                                unsigned short* __restrict__ adjb){
  const int wid = threadIdx.x >> 6, l = threadIdx.x & 63;
  const int row = blockIdx.x * 4 + wid;
  float s = 0.f;
  if(*flagp){
    const u16x8* rp = (const u16x8*)((const unsigned short*)adjv + (size_t)row * NN);
    #pragma unroll
    for(int it = 0; it < 16; ++it){
      u16x8 v = rp[it * 64 + l];
      #pragma unroll
      for(int j = 0; j < 8; ++j) s += b2f(v[j]);
    }
  } else {
    const f32x4* rp = (const f32x4*)((const float*)adjv + (size_t)row * NN);
    u16x4* wp = (u16x4*)(adjb + (size_t)row * NN);
    #pragma unroll
    for(int it = 0; it < 32; ++it){
      f32x4 v = rp[it * 64 + l];
      s += v[0] + v[1] + v[2] + v[3];
      u16x4 w;
      w[0] = f2b(v[0]); w[1] = f2b(v[1]); w[2] = f2b(v[2]); w[3] = f2b(v[3]);
      wp[it * 64 + l] = w;
    }
  }
  #pragma unroll
  for(int m = 32; m > 0; m >>= 1) s += __shfl_xor(s, m, 64);
  if(l == 0) isd[row] = (s > 0.f) ? rsqrtf(fmaxf(s, 1e-12f)) : 0.f;
}

// ---------------- hA0 = bf16(concat(pos, emb) * isd) ----------------
__global__ __launch_bounds__(256) void k_hA0(const void* __restrict__ pos,
                                             const void* __restrict__ emb,
                                             const int* __restrict__ flagp,
                                             const float* __restrict__ isd,
                                             unsigned short* __restrict__ hA){
  const int x = blockIdx.x * 256 + threadIdx.x;
  const int r = x >> 7, c = x & 127;
  float v;
  if(*flagp){
    v = b2f(c < 3 ? ((const unsigned short*)pos)[r * 3 + c]
                  : ((const unsigned short*)emb)[r * 125 + (c - 3)]);
  } else {
    v = (c < 3) ? ((const float*)pos)[r * 3 + c]
                : ((const float*)emb)[r * 125 + (c - 3)];
  }
  hA[x] = f2b(v * isd[r]);
}

// ---------------- W transpose to bf16: Wt[l][c][i] = bf16(Ws[l][i][c]) ----------------
__global__ __launch_bounds__(256) void k_wt(const void* __restrict__ Ws,
                                            const int* __restrict__ flagp,
                                            unsigned short* __restrict__ Wt){
  const int x = blockIdx.x * 256 + threadIdx.x;
  const int lyr = x >> 14, rem = x & 16383, i = rem >> 7, c = rem & 127;
  unsigned short u;
  if(*flagp) u = ((const unsigned short*)Ws)[x];
  else       u = f2b(((const float*)Ws)[x]);
  Wt[lyr * 16384 + c * 128 + i] = u;
}

// ---- makeB: Bt[c][k] = (hA @ W)^T for a 64-row tile; hA pre-scaled bf16 ----
__global__ __launch_bounds__(256) void k_makeB(const unsigned short* __restrict__ hA,
                                               const unsigned short* __restrict__ Wt,
                                               unsigned short* __restrict__ Bt){
  __shared__ char lds[49152];                 // A [0,16K), Wt [16K,48K); bounce reuses [0,18.4K)
  const int t = threadIdx.x, wid = t >> 6, l = t & 63;
  const int r0 = blockIdx.x * 64;

  // stage A rows (64 x 256B), pre-swizzled source
  #pragma unroll
  for(int q = 0; q < 4; ++q){
    int ob = q * 4096 + wid * 1024;
    int o  = ob + l * 16;
    int r  = o >> 8, x = o & 255;
    gld_lds16((const char*)hA + ((size_t)(r0 + r) << 8) + (x ^ ((r & 7) << 4)), lds + ob);
  }
  // stage Wt (128 x 256B), pre-swizzled source
  #pragma unroll
  for(int q = 0; q < 8; ++q){
    int ob = q * 4096 + wid * 1024;
    int o  = ob + l * 16;
    int c  = o >> 8, x = o & 255;
    gld_lds16((const char*)Wt + c * 256 + (x ^ ((c & 7) << 4)), lds + 16384 + ob);
  }
  __syncthreads();

  const int wm = wid >> 1, wn = wid & 1;      // wave tile: 32 rows x 64 cols
  f32x16 acc[2];
  #pragma unroll
  for(int b = 0; b < 2; ++b)
    #pragma unroll
    for(int r2 = 0; r2 < 16; ++r2) acc[b][r2] = 0.f;

  const int rlo = l & 31;
  const int swz = (l & 7) << 4;
  #pragma unroll
  for(int s = 0; s < 8; ++s){
    int ko = (s * 32 + ((l >> 5) << 4)) ^ swz;
    bf16x8 a  = *(const bf16x8*)(lds + (wm * 32 + rlo) * 256 + ko);
    bf16x8 b0 = *(const bf16x8*)(lds + 16384 + (wn * 64 +      rlo) * 256 + ko);
    bf16x8 b1 = *(const bf16x8*)(lds + 16384 + (wn * 64 + 32 + rlo) * 256 + ko);
    acc[0] = __builtin_amdgcn_mfma_f32_32x32x16_bf16(a, b0, acc[0], 0, 0, 0);
    acc[1] = __builtin_amdgcn_mfma_f32_32x32x16_bf16(a, b1, acc[1], 0, 0, 0);
  }
  __syncthreads();
  // bounce transpose into [128 c][72 r] u16 (144 B rows, 16B-aligned)
  #pragma unroll
  for(int ni = 0; ni < 2; ++ni){
    int c = wn * 64 + ni * 32 + rlo;
    #pragma unroll
    for(int reg = 0; reg < 16; ++reg){
      int r = wm * 32 + (reg & 3) + 8 * (reg >> 2) + 4 * (l >> 5);
      *(unsigned short*)(lds + c * 144 + r * 2) = f2b(acc[ni][reg]);
    }
  }
  __syncthreads();
  // write 128 c x 64 r: 1024 chunks of 16B
  #pragma unroll
  for(int q = 0; q < 4; ++q){
    int id = q * 256 + t;
    int c = id >> 3, xc = id & 7;
    u16x8 v = *(const u16x8*)(lds + c * 144 + xc * 16);
    *(u16x8*)((char*)Bt + (size_t)c * (NN * 2) + (size_t)r0 * 2 + xc * 16) = v;
  }
}

// ------ main GEMM: BM=256, BN=128, BK=32, 8 waves, KSPLIT=8
//        3-buffer distance-2 pipeline with counted vmcnt (no vmcnt(0) in loop) ------
__global__ __launch_bounds__(512, 4) void k_gemm(const void* __restrict__ adj_in,
                                                 const unsigned short* __restrict__ adjb,
                                                 const unsigned short* __restrict__ Bt,
                                                 const int* __restrict__ flagp,
                                                 float* __restrict__ partial){
  __shared__ char lds[73728];                 // 3 bufs x (A 16KiB + B 8KiB), 64B rows
  const int t = threadIdx.x, wid = t >> 6, l = t & 63;
  const int r0 = blockIdx.x * 256;
  const int kbase = blockIdx.y * 1024;
  const unsigned short* A = (*flagp) ? (const unsigned short*)adj_in : adjb;

  // 3 gld_lds16 instructions per wave per stage
  auto stage = [&](int buf, int kt){
    const int bb = buf * 24576;
    #pragma unroll
    for(int q = 0; q < 2; ++q){               // A: 256 rows x 64B
      int ob = q * 8192 + wid * 1024;
      int o = ob + l * 16;
      int row = o >> 6, x = o & 63;
      gld_lds16((const char*)A + ((size_t)(r0 + row) * NN + kt) * 2
                + (x ^ (((row >> 1) & 3) << 4)), lds + bb + ob);
    }
    {                                         // B: 128 cols x 64B
      int ob = wid * 1024;
      int o = ob + l * 16;
      int c = o >> 6, x = o & 63;
      gld_lds16((const char*)Bt + ((size_t)c * NN + kt) * 2
                + (x ^ (((c >> 1) & 3) << 4)), lds + bb + 16384 + ob);
    }
  };

  const int wr = wid >> 1, wc = wid & 1;      // wave tile: 64 rows x 64 cols
  f32x16 acc[2][2];
  #pragma unroll
  for(int a = 0; a < 2; ++a)
    #pragma unroll
    for(int b = 0; b < 2; ++b)
      #pragma unroll
      for(int r2 = 0; r2 < 16; ++r2) acc[a][b][r2] = 0.f;

  const int rlo = l & 31;
  const int swz = ((l >> 1) & 3) << 4;
  const int khalf = (l >> 5) << 4;

  auto compute = [&](int buf){
    const int bb = buf * 24576;
    #pragma unroll
    for(int kk = 0; kk < 2; ++kk){
      int ko = (kk * 32 + khalf) ^ swz;
      bf16x8 a0 = *(const bf16x8*)(lds + bb +         (wr * 64 + rlo)      * 64 + ko);
      bf16x8 a1 = *(const bf16x8*)(lds + bb +         (wr * 64 + rlo + 32) * 64 + ko);
      bf16x8 b0 = *(const bf16x8*)(lds + bb + 16384 + (wc * 64 + rlo)      * 64 + ko);
      bf16x8 b1 = *(const bf16x8*)(lds + bb + 16384 + (wc * 64 + rlo + 32) * 64 + ko);
      acc[0][0] = __builtin_amdgcn_mfma_f32_32x32x16_bf16(a0, b0, acc[0][0], 0, 0, 0);
      acc[0][1] = __builtin_amdgcn_mfma_f32_32x32x16_bf16(a0, b1, acc[0][1], 0, 0, 0);
      acc[1][0] = __builtin_amdgcn_mfma_f32_32x32x16_bf16(a1, b0, acc[1][0], 0, 0, 0);
      acc[1][1] = __builtin_amdgcn_mfma_f32_32x32x16_bf16(a1, b1, acc[1][1], 0, 0, 0);
    }
  };

  stage(0, kbase);
  stage(1, kbase + 32);
  // main loop: iters 0..30; last iter (31) peeled with full drain
  for(int it = 0; it < 31; ++it){
    // wait own stage-it loads (leave the newer stage's 3 in flight)
    asm volatile("s_waitcnt vmcnt(3)" ::: "memory");
    __builtin_amdgcn_s_barrier();             // all waves' stage-it data now in LDS
    __builtin_amdgcn_sched_barrier(0);
    if(it < 30) stage((it + 2) % 3, kbase + (it + 2) * 32);  // WAR-safe: readers passed barrier
    compute(it % 3);
  }
  asm volatile("s_waitcnt vmcnt(0)" ::: "memory");
  __builtin_amdgcn_s_barrier();
  __builtin_amdgcn_sched_barrier(0);
  compute(31 % 3);

  float* pp = partial + ((size_t)blockIdx.y << 20);
  #pragma unroll
  for(int mi = 0; mi < 2; ++mi)
    #pragma unroll
    for(int ni = 0; ni < 2; ++ni)
      #pragma unroll
      for(int reg = 0; reg < 16; ++reg){
        int r = r0 + wr * 64 + mi * 32 + (reg & 3) + 8 * (reg >> 2) + 4 * (l >> 5);
        int c = wc * 64 + ni * 32 + rlo;
        pp[(size_t)r * HID + c] = acc[mi][ni][reg];
      }
}

// ------ epilogue (full grid): reduce 8 partials + norm + bias + softplus ------
template<bool LAST>
__global__ __launch_bounds__(256) void k_epi(const float* __restrict__ partial,
                                             const float* __restrict__ isd,
                                             const void* __restrict__ bsv,
                                             int lyr, const int* __restrict__ flagp,
                                             unsigned short* __restrict__ hA,
                                             void* __restrict__ out){
  const int x = blockIdx.x * 256 + threadIdx.x;
  float v = 0.f;
  #pragma unroll
  for(int p = 0; p < 8; ++p) v += partial[((size_t)p << 20) + x];
  const int r = x >> 7, c = x & 127;
  const int mode = *flagp;
  float b = mode ? b2f(((const unsigned short*)bsv)[lyr * 128 + c])
                 : ((const float*)bsv)[lyr * 128 + c];
  float sc = isd[r];
  v = v * sc + b;
  float sp = fmaxf(v, 0.f) + log1pf(expf(-fabsf(v)));   // stable softplus
  if(LAST){
    if(mode) ((unsigned short*)out)[x] = f2b(sp);
    else     ((float*)out)[x] = sp;
  } else {
    hA[x] = f2b(sp * sc);                                // pre-scale for next layer
  }
}

extern "C" void kernel_launch(void* const* d_in, const int* in_sizes, int n_in,
                              void* d_out, int out_size, void* d_ws, size_t ws_size,
                              hipStream_t stream){
  const void* pos = d_in[0];
  const void* emb = d_in[1];
  const void* adj = d_in[2];
  const void* Ws  = d_in[3];
  const void* bs  = d_in[4];

  // ws: flag@0 | isd@0x1000 | hA@0x10000 (2M) | Bt@0x210000 (2M)
  //     Wt@0x410000 (128K) | partial@0x430000 (32M) | adjb@0x2430000 (128M)
  char* ws = (char*)d_ws;
  int*            flag    = (int*)(ws);
  float*          isd     = (float*)(ws + 0x1000);
  unsigned short* hA      = (unsigned short*)(ws + 0x10000);
  unsigned short* Bt      = (unsigned short*)(ws + 0x210000);
  unsigned short* Wt      = (unsigned short*)(ws + 0x410000);
  float*          partial = (float*)(ws + 0x430000);
  unsigned short* adjb    = (unsigned short*)(ws + 0x2430000);

  k_detect<<<1,    256, 0, stream>>>((const unsigned int*)adj, flag);
  k_degcvt<<<2048, 256, 0, stream>>>(adj, flag, isd, adjb);
  k_hA0   <<<4096, 256, 0, stream>>>(pos, emb, flag, isd, hA);
  k_wt    <<<256,  256, 0, stream>>>(Ws, flag, Wt);

  for(int lyr = 0; lyr < 4; ++lyr){
    k_makeB<<<128, 256, 0, stream>>>(hA, Wt + lyr * 16384, Bt);
    k_gemm <<<dim3(32, 8), 512, 0, stream>>>(adj, adjb, Bt, flag, partial);
    if(lyr < 3) k_epi<false><<<4096, 256, 0, stream>>>(partial, isd, bs, lyr, flag, hA, nullptr);
    else        k_epi<true ><<<4096, 256, 0, stream>>>(partial, isd, bs, lyr, flag, nullptr, d_out);
  }
}

// Round 8
// 252.489 us; speedup vs baseline: 1.9830x; 1.0210x over previous
//
#include <hip/hip_runtime.h>
#include <hip/hip_bf16.h>
#include <cstdint>

#define NN   8192
#define HID  128

typedef __attribute__((ext_vector_type(8)))  __bf16          bf16x8;
typedef __attribute__((ext_vector_type(16))) float           f32x16;
typedef __attribute__((ext_vector_type(8)))  unsigned short  u16x8;
typedef __attribute__((ext_vector_type(4)))  unsigned short  u16x4;
typedef __attribute__((ext_vector_type(4)))  float           f32x4;

__device__ __forceinline__ float b2f(unsigned short u){
  union { unsigned int i; float f; } v; v.i = ((unsigned int)u) << 16; return v.f;
}
__device__ __forceinline__ unsigned short f2b(float f){
  unsigned int i = __float_as_uint(f);
  unsigned int r = (i + 0x7FFFu + ((i >> 16) & 1u)) >> 16;   // RNE
  return (unsigned short)r;
}
__device__ __forceinline__ void gld_lds16(const void* g, void* l){
  __builtin_amdgcn_global_load_lds((const __attribute__((address_space(1))) unsigned int*)g,
                                   (__attribute__((address_space(3))) unsigned int*)l, 16, 0, 0);
}

// ---------------- dtype detect: bf16 buffers -> flag=1, f32 -> flag=0 ----------------
__global__ __launch_bounds__(256) void k_detect(const unsigned int* __restrict__ a,
                                                int* __restrict__ flag){
  __shared__ int cnt;
  if(threadIdx.x == 0) cnt = 0;
  __syncthreads();
  int c = 0;
  #pragma unroll
  for(int i = 0; i < 16; ++i){
    unsigned int w = a[i * 256 + threadIdx.x];
    c += (((w >> 8) & 0xC0u) == 0u) ? 1 : 0;
  }
  atomicAdd(&cnt, c);
  __syncthreads();
  if(threadIdx.x == 0) *flag = (cnt > 3000) ? 1 : 0;
}

// -------- deg + inv_sqrt_deg, fused f32->bf16 adj convert (one wave per row) --------
__global__ __launch_bounds__(256) void k_degcvt(const void* __restrict__ adjv,
                                                const int* __restrict__ flagp,
                                                float* __restrict__ isd,
                                                unsigned short* __restrict__ adjb){
  const int wid = threadIdx.x >> 6, l = threadIdx.x & 63;
  const int row = blockIdx.x * 4 + wid;
  float s = 0.f;
  if(*flagp){
    const u16x8* rp = (const u16x8*)((const unsigned short*)adjv + (size_t)row * NN);
    #pragma unroll
    for(int it = 0; it < 16; ++it){
      u16x8 v = rp[it * 64 + l];
      #pragma unroll
      for(int j = 0; j < 8; ++j) s += b2f(v[j]);
    }
  } else {
    const f32x4* rp = (const f32x4*)((const float*)adjv + (size_t)row * NN);
    u16x4* wp = (u16x4*)(adjb + (size_t)row * NN);
    #pragma unroll
    for(int it = 0; it < 32; ++it){
      f32x4 v = rp[it * 64 + l];
      s += v[0] + v[1] + v[2] + v[3];
      u16x4 w;
      w[0] = f2b(v[0]); w[1] = f2b(v[1]); w[2] = f2b(v[2]); w[3] = f2b(v[3]);
      wp[it * 64 + l] = w;
    }
  }
  #pragma unroll
  for(int m = 32; m > 0; m >>= 1) s += __shfl_xor(s, m, 64);
  if(l == 0) isd[row] = (s > 0.f) ? rsqrtf(fmaxf(s, 1e-12f)) : 0.f;
}

// ---------------- hA0 = bf16(concat(pos, emb) * isd) ----------------
__global__ __launch_bounds__(256) void k_hA0(const void* __restrict__ pos,
                                             const void* __restrict__ emb,
                                             const int* __restrict__ flagp,
                                             const float* __restrict__ isd,
                                             unsigned short* __restrict__ hA){
  const int x = blockIdx.x * 256 + threadIdx.x;
  const int r = x >> 7, c = x & 127;
  float v;
  if(*flagp){
    v = b2f(c < 3 ? ((const unsigned short*)pos)[r * 3 + c]
                  : ((const unsigned short*)emb)[r * 125 + (c - 3)]);
  } else {
    v = (c < 3) ? ((const float*)pos)[r * 3 + c]
                : ((const float*)emb)[r * 125 + (c - 3)];
  }
  hA[x] = f2b(v * isd[r]);
}

// ---------------- W transpose to bf16: Wt[l][c][i] = bf16(Ws[l][i][c]) ----------------
__global__ __launch_bounds__(256) void k_wt(const void* __restrict__ Ws,
                                            const int* __restrict__ flagp,
                                            unsigned short* __restrict__ Wt){
  const int x = blockIdx.x * 256 + threadIdx.x;
  const int lyr = x >> 14, rem = x & 16383, i = rem >> 7, c = rem & 127;
  unsigned short u;
  if(*flagp) u = ((const unsigned short*)Ws)[x];
  else       u = f2b(((const float*)Ws)[x]);
  Wt[lyr * 16384 + c * 128 + i] = u;
}

// ---- makeB: Bt[c][k] = (hA @ W)^T for a 64-row tile; hA pre-scaled bf16 ----
__global__ __launch_bounds__(256) void k_makeB(const unsigned short* __restrict__ hA,
                                               const unsigned short* __restrict__ Wt,
                                               unsigned short* __restrict__ Bt){
  __shared__ char lds[49152];                 // A [0,16K), Wt [16K,48K); bounce reuses [0,18.4K)
  const int t = threadIdx.x, wid = t >> 6, l = t & 63;
  const int r0 = blockIdx.x * 64;

  // stage A rows (64 x 256B), pre-swizzled source
  #pragma unroll
  for(int q = 0; q < 4; ++q){
    int ob = q * 4096 + wid * 1024;
    int o  = ob + l * 16;
    int r  = o >> 8, x = o & 255;
    gld_lds16((const char*)hA + ((size_t)(r0 + r) << 8) + (x ^ ((r & 7) << 4)), lds + ob);
  }
  // stage Wt (128 x 256B), pre-swizzled source
  #pragma unroll
  for(int q = 0; q < 8; ++q){
    int ob = q * 4096 + wid * 1024;
    int o  = ob + l * 16;
    int c  = o >> 8, x = o & 255;
    gld_lds16((const char*)Wt + c * 256 + (x ^ ((c & 7) << 4)), lds + 16384 + ob);
  }
  __syncthreads();

  const int wm = wid >> 1, wn = wid & 1;      // wave tile: 32 rows x 64 cols
  f32x16 acc[2];
  #pragma unroll
  for(int b = 0; b < 2; ++b)
    #pragma unroll
    for(int r2 = 0; r2 < 16; ++r2) acc[b][r2] = 0.f;

  const int rlo = l & 31;
  const int swz = (l & 7) << 4;
  #pragma unroll
  for(int s = 0; s < 8; ++s){
    int ko = (s * 32 + ((l >> 5) << 4)) ^ swz;
    bf16x8 a  = *(const bf16x8*)(lds + (wm * 32 + rlo) * 256 + ko);
    bf16x8 b0 = *(const bf16x8*)(lds + 16384 + (wn * 64 +      rlo) * 256 + ko);
    bf16x8 b1 = *(const bf16x8*)(lds + 16384 + (wn * 64 + 32 + rlo) * 256 + ko);
    acc[0] = __builtin_amdgcn_mfma_f32_32x32x16_bf16(a, b0, acc[0], 0, 0, 0);
    acc[1] = __builtin_amdgcn_mfma_f32_32x32x16_bf16(a, b1, acc[1], 0, 0, 0);
  }
  __syncthreads();
  // bounce transpose into [128 c][72 r] u16 (144 B rows, 16B-aligned)
  #pragma unroll
  for(int ni = 0; ni < 2; ++ni){
    int c = wn * 64 + ni * 32 + rlo;
    #pragma unroll
    for(int reg = 0; reg < 16; ++reg){
      int r = wm * 32 + (reg & 3) + 8 * (reg >> 2) + 4 * (l >> 5);
      *(unsigned short*)(lds + c * 144 + r * 2) = f2b(acc[ni][reg]);
    }
  }
  __syncthreads();
  // write 128 c x 64 r: 1024 chunks of 16B
  #pragma unroll
  for(int q = 0; q < 4; ++q){
    int id = q * 256 + t;
    int c = id >> 3, xc = id & 7;
    u16x8 v = *(const u16x8*)(lds + c * 144 + xc * 16);
    *(u16x8*)((char*)Bt + (size_t)c * (NN * 2) + (size_t)r0 * 2 + xc * 16) = v;
  }
}

// ------ main GEMM: BM=128, BN=128, BK=32, 8 waves (32x64 wave tile), KSPLIT=4
//        3-buffer distance-2 pipeline with counted vmcnt (no vmcnt(0) in loop) ------
__global__ __launch_bounds__(512, 4) void k_gemm(const void* __restrict__ adj_in,
                                                 const unsigned short* __restrict__ adjb,
                                                 const unsigned short* __restrict__ Bt,
                                                 const int* __restrict__ flagp,
                                                 float* __restrict__ partial){
  __shared__ char lds[49152];                 // 3 bufs x (A 8KiB + B 8KiB), 64B rows
  const int t = threadIdx.x, wid = t >> 6, l = t & 63;
  const int r0 = blockIdx.x * 128;
  const int kbase = blockIdx.y * 2048;
  const unsigned short* A = (*flagp) ? (const unsigned short*)adj_in : adjb;

  // 2 gld_lds16 instructions per wave per stage (A 8KB + B 8KB per block)
  auto stage = [&](int buf, int kt){
    const int bb = buf * 16384;
    {                                         // A: 128 rows x 64B
      int ob = wid * 1024;
      int o = ob + l * 16;
      int row = o >> 6, x = o & 63;
      gld_lds16((const char*)A + ((size_t)(r0 + row) * NN + kt) * 2
                + (x ^ (((row >> 1) & 3) << 4)), lds + bb + ob);
    }
    {                                         // B: 128 cols x 64B
      int ob = wid * 1024;
      int o = ob + l * 16;
      int c = o >> 6, x = o & 63;
      gld_lds16((const char*)Bt + ((size_t)c * NN + kt) * 2
                + (x ^ (((c >> 1) & 3) << 4)), lds + bb + 8192 + ob);
    }
  };

  const int wr = wid >> 1, wc = wid & 1;      // wave tile: 32 rows x 64 cols
  f32x16 acc[2];
  #pragma unroll
  for(int b = 0; b < 2; ++b)
    #pragma unroll
    for(int r2 = 0; r2 < 16; ++r2) acc[b][r2] = 0.f;

  const int rlo = l & 31;
  const int swz = ((l >> 1) & 3) << 4;
  const int khalf = (l >> 5) << 4;

  auto compute = [&](int buf){
    const int bb = buf * 16384;
    #pragma unroll
    for(int kk = 0; kk < 2; ++kk){
      int ko = (kk * 32 + khalf) ^ swz;
      bf16x8 a  = *(const bf16x8*)(lds + bb +        (wr * 32 + rlo)      * 64 + ko);
      bf16x8 b0 = *(const bf16x8*)(lds + bb + 8192 + (wc * 64 + rlo)      * 64 + ko);
      bf16x8 b1 = *(const bf16x8*)(lds + bb + 8192 + (wc * 64 + rlo + 32) * 64 + ko);
      acc[0] = __builtin_amdgcn_mfma_f32_32x32x16_bf16(a, b0, acc[0], 0, 0, 0);
      acc[1] = __builtin_amdgcn_mfma_f32_32x32x16_bf16(a, b1, acc[1], 0, 0, 0);
    }
  };

  stage(0, kbase);
  stage(1, kbase + 32);
  // 64 K-iters total: loop 0..62, iter 63 peeled with full drain
  for(int it = 0; it < 63; ++it){
    asm volatile("s_waitcnt vmcnt(2)" ::: "memory");   // wait own stage-it loads
    __builtin_amdgcn_s_barrier();
    __builtin_amdgcn_sched_barrier(0);
    if(it < 62) stage((it + 2) % 3, kbase + (it + 2) * 32);  // WAR-safe post-barrier
    compute(it % 3);
  }
  asm volatile("s_waitcnt vmcnt(0)" ::: "memory");
  __builtin_amdgcn_s_barrier();
  __builtin_amdgcn_sched_barrier(0);
  compute(63 % 3);

  float* pp = partial + ((size_t)blockIdx.y << 20);
  #pragma unroll
  for(int ni = 0; ni < 2; ++ni)
    #pragma unroll
    for(int reg = 0; reg < 16; ++reg){
      int r = r0 + wr * 32 + (reg & 3) + 8 * (reg >> 2) + 4 * (l >> 5);
      int c = wc * 64 + ni * 32 + rlo;
      pp[(size_t)r * HID + c] = acc[ni][reg];
    }
}

// ------ epilogue (full grid): reduce 4 partials + norm + bias + softplus ------
template<bool LAST>
__global__ __launch_bounds__(256) void k_epi(const float* __restrict__ partial,
                                             const float* __restrict__ isd,
                                             const void* __restrict__ bsv,
                                             int lyr, const int* __restrict__ flagp,
                                             unsigned short* __restrict__ hA,
                                             void* __restrict__ out){
  const int x = blockIdx.x * 256 + threadIdx.x;
  float v = 0.f;
  #pragma unroll
  for(int p = 0; p < 4; ++p) v += partial[((size_t)p << 20) + x];
  const int r = x >> 7, c = x & 127;
  const int mode = *flagp;
  float b = mode ? b2f(((const unsigned short*)bsv)[lyr * 128 + c])
                 : ((const float*)bsv)[lyr * 128 + c];
  float sc = isd[r];
  v = v * sc + b;
  float sp = fmaxf(v, 0.f) + log1pf(expf(-fabsf(v)));   // stable softplus
  if(LAST){
    if(mode) ((unsigned short*)out)[x] = f2b(sp);
    else     ((float*)out)[x] = sp;
  } else {
    hA[x] = f2b(sp * sc);                                // pre-scale for next layer
  }
}

extern "C" void kernel_launch(void* const* d_in, const int* in_sizes, int n_in,
                              void* d_out, int out_size, void* d_ws, size_t ws_size,
                              hipStream_t stream){
  const void* pos = d_in[0];
  const void* emb = d_in[1];
  const void* adj = d_in[2];
  const void* Ws  = d_in[3];
  const void* bs  = d_in[4];

  // ws: flag@0 | isd@0x1000 | hA@0x10000 (2M) | Bt@0x210000 (2M)
  //     Wt@0x410000 (128K) | partial@0x430000 (16M) | adjb@0x2430000 (128M)
  char* ws = (char*)d_ws;
  int*            flag    = (int*)(ws);
  float*          isd     = (float*)(ws + 0x1000);
  unsigned short* hA      = (unsigned short*)(ws + 0x10000);
  unsigned short* Bt      = (unsigned short*)(ws + 0x210000);
  unsigned short* Wt      = (unsigned short*)(ws + 0x410000);
  float*          partial = (float*)(ws + 0x430000);
  unsigned short* adjb    = (unsigned short*)(ws + 0x2430000);

  k_detect<<<1,    256, 0, stream>>>((const unsigned int*)adj, flag);
  k_degcvt<<<2048, 256, 0, stream>>>(adj, flag, isd, adjb);
  k_hA0   <<<4096, 256, 0, stream>>>(pos, emb, flag, isd, hA);
  k_wt    <<<256,  256, 0, stream>>>(Ws, flag, Wt);

  for(int lyr = 0; lyr < 4; ++lyr){
    k_makeB<<<128, 256, 0, stream>>>(hA, Wt + lyr * 16384, Bt);
    k_gemm <<<dim3(64, 4), 512, 0, stream>>>(adj, adjb, Bt, flag, partial);
    if(lyr < 3) k_epi<false><<<4096, 256, 0, stream>>>(partial, isd, bs, lyr, flag, hA, nullptr);
    else        k_epi<true ><<<4096, 256, 0, stream>>>(partial, isd, bs, lyr, flag, nullptr, d_out);
  }
}